// Round 9
// baseline (80.756 us; speedup 1.0000x reference)
//
#include <hip/hip_runtime.h>
#include <stdint.h>

// ---------------------------------------------------------------------------
// FractalLinear: IFS chaos game (JAX threefry-exact) + bilinear gather/scatter
// Round 9 structure:
//   K1 chaos (8 lanes/point, 32 blocks) -> rec[1000] = {xl, xw, yl, yw}
//   K2 build (1 block): touched-bin compaction. U<=2000 distinct y-bins,
//      bins[U] (compact->column), per-point packed compact pair, 8192b bitmap.
//   K3 apply (1 row/block, 256 thr, 9KB LDS -> 8 blk/CU, ONE generation):
//      ph0: stream out=bias for untouched columns (bitmap-predicated,
//           nontemporal) -- independent of gather, overlaps its latency
//      ph1: gather 4 pts/thread + LDS atomic scatter into 2048-float acc
//      ph2: scattered overwrite of the U touched columns
// ---------------------------------------------------------------------------
#ifndef PRNG_PARTITIONABLE
#define PRNG_PARTITIONABLE 1
#endif

namespace {

constexpr int kH  = 8192;
constexpr int kW  = 16384;
constexpr int kNT = 8;
constexpr int kNP = 1000;
constexpr int kCI = 10;
constexpr int kU  = 2048;           // compact-acc capacity (>= max distinct bins)

// ws layout (byte offsets, 16B-aligned)
constexpr size_t kOffRec    = 0;        // 1000 * int4 = 16000
constexpr size_t kOffRec2   = 16384;    // 1000 * int4 = 16000
constexpr size_t kOffBins   = 32768;    // 2048 * u32  = 8192
constexpr size_t kOffBitmap = 40960;    // 256 * u32   = 1024
constexpr size_t kOffHdr    = 41984;    // u32 U

typedef float floatx4 __attribute__((ext_vector_type(4)));  // nontemporal-OK

__device__ __forceinline__ uint32_t rotl32(uint32_t x, int n) {
  return (x << n) | (x >> (32 - n));
}

// Threefry-2x32, 20 rounds (Random123 / JAX convention).
__device__ void threefry2x32(uint32_t k0, uint32_t k1, uint32_t c0, uint32_t c1,
                             uint32_t& o0, uint32_t& o1) {
  const uint32_t ks2 = k0 ^ k1 ^ 0x1BD11BDAu;
  uint32_t x0 = c0 + k0, x1 = c1 + k1;
#define TF_R(r) { x0 += x1; x1 = rotl32(x1, (r)); x1 ^= x0; }
  TF_R(13) TF_R(15) TF_R(26) TF_R(6)
  x0 += k1;  x1 += ks2 + 1u;
  TF_R(17) TF_R(29) TF_R(16) TF_R(24)
  x0 += ks2; x1 += k0 + 2u;
  TF_R(13) TF_R(15) TF_R(26) TF_R(6)
  x0 += k0;  x1 += k1 + 3u;
  TF_R(17) TF_R(29) TF_R(16) TF_R(24)
  x0 += k1;  x1 += ks2 + 4u;
  TF_R(13) TF_R(15) TF_R(26) TF_R(6)
  x0 += ks2; x1 += k0 + 5u;
#undef TF_R
  o0 = x0; o1 = x1;
}

__device__ __forceinline__ uint32_t random_bits32(uint32_t k0, uint32_t k1,
                                                  uint32_t i, uint32_t size) {
#if PRNG_PARTITIONABLE
  uint32_t o0, o1;
  threefry2x32(k0, k1, 0u /* hi(i) */, i, o0, o1);
  (void)size;
  return o0 ^ o1;
#else
  const uint32_t half = size / 2u;
  const uint32_t j = (i < half) ? i : (i - half);
  uint32_t o0, o1;
  threefry2x32(k0, k1, j, j + half, o0, o1);
  return (i < half) ? o0 : o1;
#endif
}

__device__ __forceinline__ float u01(uint32_t bits) {
  return __uint_as_float((bits >> 9) | 0x3f800000u) - 1.0f;
}

// x86 cvttss2si semantics: out-of-range / NaN -> INT_MIN (matches CPU-ref).
__device__ __forceinline__ int cvt_f32_i32_x86(float v) {
  if (!(v >= -2147483648.0f && v < 2147483648.0f)) return (int)0x80000000;
  return (int)v;
}

// ---------------------------------------------------------------------------
// Kernel 1: chaos game, 8 lanes per point (one transform each).
// ---------------------------------------------------------------------------
__global__ __launch_bounds__(256) void fractal_chaos(
    const float* __restrict__ dna, int4* __restrict__ rec) {
  const int gid  = blockIdx.x * blockDim.x + threadIdx.x;
  const int n    = gid >> 3;
  const int lane = gid & 7;
  if (n >= kNP) return;

  uint32_t kp0, kp1, kg0, kg1;
#if PRNG_PARTITIONABLE
  threefry2x32(0u, 1u, 0u, 0u, kp0, kp1);
  threefry2x32(0u, 1u, 0u, 1u, kg0, kg1);
#else
  uint32_t a0, a1, b0, b1;
  threefry2x32(0u, 1u, 0u, 2u, a0, a1);
  threefry2x32(0u, 1u, 1u, 3u, b0, b1);
  kp0 = a0; kp1 = b0; kg0 = a1; kg1 = b1;
#endif

  const float A  = dna[lane * 7 + 0], Bb = dna[lane * 7 + 1];
  const float C  = dna[lane * 7 + 2], D  = dna[lane * 7 + 3];
  const float E  = dna[lane * 7 + 4], F  = dna[lane * 7 + 5];
  const float P  = dna[lane * 7 + 6];

  float z[kCI];
  #pragma unroll
  for (int i = 0; i < kCI; ++i) {
    uint32_t ki0, ki1;
    threefry2x32(kg0, kg1, 0u, (uint32_t)i, ki0, ki1);   // fold_in(kg, i)
    const uint32_t bb = random_bits32(ki0, ki1, (uint32_t)(n * kNT + lane),
                                      (uint32_t)(kNP * kNT));
    const float u = fmaxf(u01(bb), 1.17549435e-38f);
    const float g = -logf(-logf(u));
    z[i] = P + g;
  }

  const uint32_t bx = random_bits32(kp0, kp1, (uint32_t)(2 * n),     2u * kNP);
  const uint32_t by = random_bits32(kp0, kp1, (uint32_t)(2 * n + 1), 2u * kNP);
  float px = u01(bx) * 2.0f - 1.0f;
  float py = u01(by) * 2.0f - 1.0f;

  #pragma unroll
  for (int i = 0; i < kCI; ++i) {
    // argmax over the 8 lanes, first-index tiebreak (matches jnp.argmax)
    float zb = z[i];
    int   bt = lane;
    #pragma unroll
    for (int m = 1; m < 8; m <<= 1) {
      const float zo = __shfl_xor(zb, m, 8);
      const int   to = __shfl_xor(bt, m, 8);
      if (zo > zb || (zo == zb && to < bt)) { zb = zo; bt = to; }
    }
    const float A_ = __shfl(A,  bt, 8), B_ = __shfl(Bb, bt, 8);
    const float C_ = __shfl(C,  bt, 8), D_ = __shfl(D,  bt, 8);
    const float E_ = __shfl(E,  bt, 8), F_ = __shfl(F,  bt, 8);
    const float nx = A_ * px + B_ * py + E_;
    const float ny = C_ * px + D_ * py + F_;
    px = nx; py = ny;
  }

  if (lane == 0) {
    const float xc = ((px + 1.0f) * 0.5f) * (float)(kW - 1);
    const float yc = ((py + 1.0f) * 0.5f) * (float)(kH - 1);
    int xl = cvt_f32_i32_x86(floorf(xc));
    int yl = cvt_f32_i32_x86(floorf(yc));
    xl = min(max(xl, 0), kW - 2);
    yl = min(max(yl, 0), kH - 2);
    const float xw = xc - (float)xl;   // NOT clipped (matches reference)
    const float yw = yc - (float)yl;
    rec[n] = make_int4(xl, __float_as_int(xw), yl, __float_as_int(yw));
  }
}

// ---------------------------------------------------------------------------
// Kernel 2 (1 block, 1024 thr): touched-bin compaction.
//   mark[8192] (0/1) -> bitmap words -> exclusive scan -> rank table,
//   bins[rank]=column, rec2[n] = {xl, xw, c0|c1<<16, yw}, hdr = U.
// Scan pattern identical to the (correctness-proven) round-7 build.
// ---------------------------------------------------------------------------
__global__ __launch_bounds__(1024) void fractal_build(
    const int4* __restrict__ rec, int4* __restrict__ rec2,
    uint32_t* __restrict__ bins, uint32_t* __restrict__ bitmap,
    uint32_t* __restrict__ hdr) {
  __shared__ uint32_t mark[kH];     // 32 KB: 0/1 marks, then rank table
  __shared__ uint32_t seg[1024];

  const int t = threadIdx.x;

  #pragma unroll
  for (int i = 0; i < kH / 1024; ++i) mark[t + i * 1024] = 0u;
  __syncthreads();

  int xl = 0, yl = 0;
  uint32_t xwb = 0, ywb = 0;
  const bool hav = t < kNP;
  if (hav) {
    const int4 r = rec[t];
    xl = r.x; xwb = (uint32_t)r.y;
    yl = r.z; ywb = (uint32_t)r.w;
    mark[yl] = 1u;              // idempotent plain stores; races benign
    mark[yl + 1] = 1u;
  }
  __syncthreads();

  // bitmap words (read-only on mark, no extra sync vs scan's read)
  if (t < kH / 32) {
    uint32_t w = 0;
    #pragma unroll
    for (int j = 0; j < 32; ++j) w |= mark[t * 32 + j] << j;
    bitmap[t] = w;
  }

  // exclusive scan over mark[8192]: 8 per thread + Hillis-Steele on seg
  uint32_t s = 0;
  #pragma unroll
  for (int i = 0; i < 8; ++i) s += mark[t * 8 + i];
  seg[t] = s;
  __syncthreads();
  #pragma unroll
  for (int o = 1; o < 1024; o <<= 1) {
    uint32_t v = (t >= o) ? seg[t - o] : 0u;
    __syncthreads();
    seg[t] += v;
    __syncthreads();
  }
  uint32_t run = (t > 0) ? seg[t - 1] : 0u;
  if (t == 1023) hdr[0] = seg[1023];             // U = total distinct bins
  #pragma unroll
  for (int i = 0; i < 8; ++i) {
    const int h = t * 8 + i;
    const uint32_t m = mark[h];
    if (m) bins[run] = (uint32_t)h;
    mark[h] = run;                               // rank table (valid if marked)
    run += m;
  }
  __syncthreads();

  if (hav) {
    const uint32_t c0 = mark[yl];
    const uint32_t c1 = mark[yl + 1];
    rec2[t] = make_int4(xl, (int)xwb, (int)(c0 | (c1 << 16)), (int)ywb);
  }
}

// ---------------------------------------------------------------------------
// Kernel 3: one row/block, 256 threads, 9.25 KB LDS (8 blk/CU, 1 generation).
// ---------------------------------------------------------------------------
__global__ __launch_bounds__(256) void fractal_apply(
    const float* __restrict__ x, const float* __restrict__ bias,
    const int4* __restrict__ rec2, const uint32_t* __restrict__ bins,
    const uint32_t* __restrict__ bitmap, const uint32_t* __restrict__ hdr,
    float* __restrict__ out) {
  __shared__ float acc[kU];             // 8 KB compact accumulator
  __shared__ uint32_t bmw[kH / 32];     // 1 KB bitmap

  const int tid = threadIdx.x;
  const int b   = blockIdx.x;
  const float* __restrict__ xrow = x + (size_t)b * kW;
  float* __restrict__ outrow = out + (size_t)b * kH;

  // zero compact acc + stage bitmap
  float4* acc4 = reinterpret_cast<float4*>(acc);
  acc4[tid]       = make_float4(0.f, 0.f, 0.f, 0.f);
  acc4[tid + 256] = make_float4(0.f, 0.f, 0.f, 0.f);
  bmw[tid] = bitmap[tid];
  const uint32_t U = hdr[0];
  __syncthreads();

  // --- ph1a: issue the 4 scattered gathers (latency overlapped by ph0) ---
  int4  r[4];
  float v0[4], v1[4];
  #pragma unroll
  for (int j = 0; j < 4; ++j) {
    const int n = tid + j * 256;
    if (n < kNP) {
      r[j] = rec2[n];
      v0[j] = xrow[r[j].x];
      v1[j] = xrow[r[j].x + 1];
    }
  }

  // --- ph0: stream out = bias for untouched columns (no dependency) ---
  const floatx4* __restrict__ bias4 = reinterpret_cast<const floatx4*>(bias);
  floatx4* __restrict__ outrow4 = reinterpret_cast<floatx4*>(outrow);
  #pragma unroll
  for (int j = 0; j < 8; ++j) {
    const int g = j * 256 + tid;                       // float4 group [0,2048)
    const floatx4 bv = bias4[g];
    const uint32_t nib = (bmw[g >> 3] >> ((g & 7) * 4)) & 0xFu;
    if (nib == 0) {
      __builtin_nontemporal_store(bv, &outrow4[g]);
    } else {                                           // touched lanes skipped
      float* o = outrow + 4 * g;
      if (!(nib & 1u)) o[0] = bv.x;
      if (!(nib & 2u)) o[1] = bv.y;
      if (!(nib & 4u)) o[2] = bv.z;
      if (!(nib & 8u)) o[3] = bv.w;
    }
  }

  // --- ph1b: bilinear weights + compact LDS scatter ---
  #pragma unroll
  for (int j = 0; j < 4; ++j) {
    const int n = tid + j * 256;
    if (n < kNP) {
      const float xw = __int_as_float(r[j].y);
      const float yw = __int_as_float(r[j].w);
      const uint32_t c01 = (uint32_t)r[j].z;
      const float xv = v0[j] * (1.0f - xw) + v1[j] * xw;
      atomicAdd(&acc[c01 & 0xFFFFu], xv * (1.0f - yw));
      atomicAdd(&acc[c01 >> 16],     xv * yw);
    }
  }
  __syncthreads();

  // --- ph2: scattered overwrite of the U touched columns ---
  for (uint32_t i = tid; i < U; i += 256) {
    const uint32_t c = bins[i];
    outrow[c] = acc[i] / 1000.0f + bias[c];
  }
}

}  // namespace

extern "C" void kernel_launch(void* const* d_in, const int* in_sizes, int n_in,
                              void* d_out, int out_size, void* d_ws, size_t ws_size,
                              hipStream_t stream) {
  const float* x    = (const float*)d_in[0];   // (2048, 16384)
  const float* dna  = (const float*)d_in[1];   // (56,)
  const float* bias = (const float*)d_in[2];   // (8192,)
  float* out = (float*)d_out;                  // (2048, 8192)

  char* ws = (char*)d_ws;
  int4*     rec    = (int4*)(ws + kOffRec);
  int4*     rec2   = (int4*)(ws + kOffRec2);
  uint32_t* bins   = (uint32_t*)(ws + kOffBins);
  uint32_t* bitmap = (uint32_t*)(ws + kOffBitmap);
  uint32_t* hdr    = (uint32_t*)(ws + kOffHdr);

  fractal_chaos<<<(kNP * 8 + 255) / 256, 256, 0, stream>>>(dna, rec);
  fractal_build<<<1, 1024, 0, stream>>>(rec, rec2, bins, bitmap, hdr);

  const int B = in_sizes[0] / kW;              // 2048
  fractal_apply<<<B, 256, 0, stream>>>(x, bias, rec2, bins, bitmap, hdr, out);
}

// Round 10
// 49.220 us; speedup vs baseline: 1.6407x; 1.6407x over previous
//
#include <hip/hip_runtime.h>
#include <stdint.h>

// ---------------------------------------------------------------------------
// FractalLinear: IFS chaos game (JAX threefry-exact) + bilinear gather/scatter
// Round 10 = round-4 structure (best, 46.5us) + xl-SORTED point order:
//   build kernel counting-sorts rec by x_low so each wave's 64 gather
//   requests are ascending/clustered (DRAM-friendly, line-coalesced)
//   instead of 64 random lines. Apply kernel otherwise identical; gather
//   loads hoisted above the LDS-zero barrier to hide their latency.
// Lesson from round 9: never fragment the output stream (masked/scattered
// stores -> partial-line RMW, WRITE 64->107MB). Full float4 lines only.
// ---------------------------------------------------------------------------
#ifndef PRNG_PARTITIONABLE
#define PRNG_PARTITIONABLE 1
#endif

namespace {

constexpr int kH  = 8192;
constexpr int kW  = 16384;
constexpr int kNT = 8;
constexpr int kNP = 1000;
constexpr int kCI = 10;
constexpr int kRPB = 2;          // batch rows per apply-block

// ws layout (byte offsets)
constexpr size_t kOffRec  = 0;        // 1000 * int4 = 16000
constexpr size_t kOffRec2 = 16384;    // 1000 * int4 = 16000 (xl-sorted)

typedef float floatx4 __attribute__((ext_vector_type(4)));  // nontemporal-OK

__device__ __forceinline__ uint32_t rotl32(uint32_t x, int n) {
  return (x << n) | (x >> (32 - n));
}

// Threefry-2x32, 20 rounds (Random123 / JAX convention).
__device__ void threefry2x32(uint32_t k0, uint32_t k1, uint32_t c0, uint32_t c1,
                             uint32_t& o0, uint32_t& o1) {
  const uint32_t ks2 = k0 ^ k1 ^ 0x1BD11BDAu;
  uint32_t x0 = c0 + k0, x1 = c1 + k1;
#define TF_R(r) { x0 += x1; x1 = rotl32(x1, (r)); x1 ^= x0; }
  TF_R(13) TF_R(15) TF_R(26) TF_R(6)
  x0 += k1;  x1 += ks2 + 1u;
  TF_R(17) TF_R(29) TF_R(16) TF_R(24)
  x0 += ks2; x1 += k0 + 2u;
  TF_R(13) TF_R(15) TF_R(26) TF_R(6)
  x0 += k0;  x1 += k1 + 3u;
  TF_R(17) TF_R(29) TF_R(16) TF_R(24)
  x0 += k1;  x1 += ks2 + 4u;
  TF_R(13) TF_R(15) TF_R(26) TF_R(6)
  x0 += ks2; x1 += k0 + 5u;
#undef TF_R
  o0 = x0; o1 = x1;
}

__device__ __forceinline__ uint32_t random_bits32(uint32_t k0, uint32_t k1,
                                                  uint32_t i, uint32_t size) {
#if PRNG_PARTITIONABLE
  uint32_t o0, o1;
  threefry2x32(k0, k1, 0u /* hi(i) */, i, o0, o1);
  (void)size;
  return o0 ^ o1;
#else
  const uint32_t half = size / 2u;
  const uint32_t j = (i < half) ? i : (i - half);
  uint32_t o0, o1;
  threefry2x32(k0, k1, j, j + half, o0, o1);
  return (i < half) ? o0 : o1;
#endif
}

__device__ __forceinline__ float u01(uint32_t bits) {
  return __uint_as_float((bits >> 9) | 0x3f800000u) - 1.0f;
}

// x86 cvttss2si semantics: out-of-range / NaN -> INT_MIN (matches CPU-ref).
__device__ __forceinline__ int cvt_f32_i32_x86(float v) {
  if (!(v >= -2147483648.0f && v < 2147483648.0f)) return (int)0x80000000;
  return (int)v;
}

// ---------------------------------------------------------------------------
// Kernel 1: chaos game, 8 lanes per point (one transform each).
// ---------------------------------------------------------------------------
__global__ __launch_bounds__(256) void fractal_chaos(
    const float* __restrict__ dna, int4* __restrict__ rec) {
  const int gid  = blockIdx.x * blockDim.x + threadIdx.x;
  const int n    = gid >> 3;
  const int lane = gid & 7;
  if (n >= kNP) return;

  uint32_t kp0, kp1, kg0, kg1;
#if PRNG_PARTITIONABLE
  threefry2x32(0u, 1u, 0u, 0u, kp0, kp1);
  threefry2x32(0u, 1u, 0u, 1u, kg0, kg1);
#else
  uint32_t a0, a1, b0, b1;
  threefry2x32(0u, 1u, 0u, 2u, a0, a1);
  threefry2x32(0u, 1u, 1u, 3u, b0, b1);
  kp0 = a0; kp1 = b0; kg0 = a1; kg1 = b1;
#endif

  const float A  = dna[lane * 7 + 0], Bb = dna[lane * 7 + 1];
  const float C  = dna[lane * 7 + 2], D  = dna[lane * 7 + 3];
  const float E  = dna[lane * 7 + 4], F  = dna[lane * 7 + 5];
  const float P  = dna[lane * 7 + 6];

  float z[kCI];
  #pragma unroll
  for (int i = 0; i < kCI; ++i) {
    uint32_t ki0, ki1;
    threefry2x32(kg0, kg1, 0u, (uint32_t)i, ki0, ki1);   // fold_in(kg, i)
    const uint32_t bb = random_bits32(ki0, ki1, (uint32_t)(n * kNT + lane),
                                      (uint32_t)(kNP * kNT));
    const float u = fmaxf(u01(bb), 1.17549435e-38f);
    const float g = -logf(-logf(u));
    z[i] = P + g;
  }

  const uint32_t bx = random_bits32(kp0, kp1, (uint32_t)(2 * n),     2u * kNP);
  const uint32_t by = random_bits32(kp0, kp1, (uint32_t)(2 * n + 1), 2u * kNP);
  float px = u01(bx) * 2.0f - 1.0f;
  float py = u01(by) * 2.0f - 1.0f;

  #pragma unroll
  for (int i = 0; i < kCI; ++i) {
    // argmax over the 8 lanes, first-index tiebreak (matches jnp.argmax)
    float zb = z[i];
    int   bt = lane;
    #pragma unroll
    for (int m = 1; m < 8; m <<= 1) {
      const float zo = __shfl_xor(zb, m, 8);
      const int   to = __shfl_xor(bt, m, 8);
      if (zo > zb || (zo == zb && to < bt)) { zb = zo; bt = to; }
    }
    const float A_ = __shfl(A,  bt, 8), B_ = __shfl(Bb, bt, 8);
    const float C_ = __shfl(C,  bt, 8), D_ = __shfl(D,  bt, 8);
    const float E_ = __shfl(E,  bt, 8), F_ = __shfl(F,  bt, 8);
    const float nx = A_ * px + B_ * py + E_;
    const float ny = C_ * px + D_ * py + F_;
    px = nx; py = ny;
  }

  if (lane == 0) {
    const float xc = ((px + 1.0f) * 0.5f) * (float)(kW - 1);
    const float yc = ((py + 1.0f) * 0.5f) * (float)(kH - 1);
    int xl = cvt_f32_i32_x86(floorf(xc));
    int yl = cvt_f32_i32_x86(floorf(yc));
    xl = min(max(xl, 0), kW - 2);
    yl = min(max(yl, 0), kH - 2);
    const float xw = xc - (float)xl;   // NOT clipped (matches reference)
    const float yw = yc - (float)yl;
    rec[n] = make_int4(xl, __float_as_int(xw), yl, __float_as_int(yw));
  }
}

// ---------------------------------------------------------------------------
// Kernel 2 (1 block, 1024 thr): counting-sort rec by x_low (1024 buckets of
// 16 columns) -> rec2. Intra-bucket order via atomic cursor (scatter in the
// apply kernel is atomicAdd, so accumulation order only jitters rounding).
// ---------------------------------------------------------------------------
__global__ __launch_bounds__(1024) void fractal_build(
    const int4* __restrict__ rec, int4* __restrict__ rec2) {
  __shared__ uint32_t cnt[1024];
  __shared__ uint32_t seg[1024];

  const int t = threadIdx.x;
  cnt[t] = 0;
  __syncthreads();

  int4 r = make_int4(0, 0, 0, 0);
  int bx = 0;
  const bool hav = t < kNP;
  if (hav) {
    r = rec[t];
    bx = r.x >> 4;
    atomicAdd(&cnt[bx], 1u);
  }
  __syncthreads();

  // exclusive scan of cnt[1024] (Hillis-Steele)
  seg[t] = cnt[t];
  __syncthreads();
  #pragma unroll
  for (int o = 1; o < 1024; o <<= 1) {
    uint32_t v = (t >= o) ? seg[t - o] : 0u;
    __syncthreads();
    seg[t] += v;
    __syncthreads();
  }
  cnt[t] = (t > 0) ? seg[t - 1] : 0u;   // exclusive offsets -> cursors
  __syncthreads();

  if (hav) {
    const uint32_t p = atomicAdd(&cnt[bx], 1u);
    rec2[p] = r;
  }
}

// ---------------------------------------------------------------------------
// Kernel 3: 2 batch rows per block, 1024 threads (round-4 structure).
// rec2 is xl-sorted: each wave's gathers hit ascending, clustered lines.
// Gather loads issued BEFORE the zero/barrier to hide latency.
// ---------------------------------------------------------------------------
__global__ __launch_bounds__(1024) void fractal_apply(
    const float* __restrict__ x, const float* __restrict__ bias,
    const int4* __restrict__ rec2, float* __restrict__ out, int B) {
  __shared__ __align__(16) float acc[kRPB * kH];
  const int b0 = blockIdx.x * kRPB;
  const int nrows = min(kRPB, B - b0);
  const int tid = threadIdx.x;

  // --- issue gather loads first (independent of LDS) ---
  const bool havept = tid < kNP;
  int4 r = make_int4(0, 0, 0, 0);
  float v0[kRPB], v1[kRPB];
  if (havept) {
    r = rec2[tid];
    const float* xp = x + (size_t)b0 * kW + r.x;
    #pragma unroll
    for (int rI = 0; rI < kRPB; ++rI) {
      if (rI < nrows) {
        v0[rI] = xp[(size_t)rI * kW];
        v1[rI] = xp[(size_t)rI * kW + 1];
      }
    }
  }

  // --- zero accumulator (overlaps gather latency) ---
  float4* acc4 = reinterpret_cast<float4*>(acc);
  constexpr int N4 = kRPB * kH / 4;            // 4096
  for (int i = tid; i < N4; i += 1024)
    acc4[i] = make_float4(0.f, 0.f, 0.f, 0.f);
  __syncthreads();

  // --- bilinear weights + LDS atomic scatter ---
  if (havept) {
    const float xw = __int_as_float(r.y);
    const float yw = __int_as_float(r.w);
    const float xw0 = 1.0f - xw;
    const float w0  = 1.0f - yw;
    const int yl = r.z;
    #pragma unroll
    for (int rI = 0; rI < kRPB; ++rI) {
      if (rI < nrows) {
        const float xv = v0[rI] * xw0 + v1[rI] * xw;
        atomicAdd(&acc[rI * kH + yl],     xv * w0);
        atomicAdd(&acc[rI * kH + yl + 1], xv * yw);
      }
    }
  }
  __syncthreads();

  // --- epilogue: out = acc/1000 + bias (full float4 lines, nontemporal) ---
  const floatx4* __restrict__ bias4 = reinterpret_cast<const floatx4*>(bias);
  for (int i = tid; i < N4; i += 1024) {
    const int row = i >> 11;          // i / (kH/4)
    const int col = i & 2047;         // i % (kH/4)
    if (row < nrows) {
      const float4 a  = acc4[i];
      const floatx4 bi = bias4[col];
      floatx4 o;
      o.x = a.x / 1000.0f + bi.x;
      o.y = a.y / 1000.0f + bi.y;
      o.z = a.z / 1000.0f + bi.z;
      o.w = a.w / 1000.0f + bi.w;
      floatx4* dst = reinterpret_cast<floatx4*>(out + (size_t)(b0 + row) * kH);
      __builtin_nontemporal_store(o, &dst[col]);
    }
  }
}

}  // namespace

extern "C" void kernel_launch(void* const* d_in, const int* in_sizes, int n_in,
                              void* d_out, int out_size, void* d_ws, size_t ws_size,
                              hipStream_t stream) {
  const float* x    = (const float*)d_in[0];   // (2048, 16384)
  const float* dna  = (const float*)d_in[1];   // (56,)
  const float* bias = (const float*)d_in[2];   // (8192,)
  float* out = (float*)d_out;                  // (2048, 8192)

  char* ws = (char*)d_ws;
  int4* rec  = (int4*)(ws + kOffRec);
  int4* rec2 = (int4*)(ws + kOffRec2);

  fractal_chaos<<<(kNP * 8 + 255) / 256, 256, 0, stream>>>(dna, rec);
  fractal_build<<<1, 1024, 0, stream>>>(rec, rec2);

  const int B = in_sizes[0] / kW;              // 2048
  fractal_apply<<<(B + kRPB - 1) / kRPB, 1024, 0, stream>>>(x, bias, rec2,
                                                            out, B);
}